// Round 3
// baseline (214.758 us; speedup 1.0000x reference)
//
#include <hip/hip_runtime.h>
#include <hip/hip_bf16.h>
#include <cstdint>
#include <cstddef>

// Problem constants
#define NB 512
#define NM 16
#define ND 128
#define NP 16
#define NT 4096

typedef __bf16 bf16x8 __attribute__((ext_vector_type(8)));
typedef float f32x4 __attribute__((ext_vector_type(4)));

static_assert(sizeof(bf16x8) == 16, "bf16x8 must be 16B");

__device__ __forceinline__ void gload_lds16(const void* g, void* l) {
  __builtin_amdgcn_global_load_lds(
      (const __attribute__((address_space(1))) unsigned int*)g,
      (__attribute__((address_space(3))) unsigned int*)l, 16, 0, 0);
}

// ---------------------------------------------------------------------------
// Kernel 1:
//  blocks [0,512): new_state[b,m,:] = tanh(state@A_m + phi@B_m)
//    -> fp32 (nt) to d_out tail, swizzled bf16 to ws, s_sq[b*16+m] to ws
//  blocks [512,544): t_sq[t] + swizzled bf16 trajectories
//  Swizzle: 16B chunk kb of row R stored at chunk (kb ^ (R&15)) -> conflict-
//  free ds_read_b128 fragment reads in kernel 2.
// ---------------------------------------------------------------------------
__global__ __launch_bounds__(256) void prep_kernel(
    const float* __restrict__ phi, const float* __restrict__ state,
    const float* __restrict__ traj, const float* __restrict__ A,
    const float* __restrict__ Bin, float* __restrict__ ns_out,
    __bf16* __restrict__ ns_bf, __bf16* __restrict__ tj_bf,
    float* __restrict__ s_sq, float* __restrict__ t_sq) {
  __shared__ alignas(16) float sSt[16 * 128];   // state rows (8 KB)
  __shared__ alignas(16) float sPhi[16 * 16];   // phi rows (1 KB)
  __shared__ alignas(16) float sRes[16 * 128];  // result tile for repack (8 KB)
  const int tid = threadIdx.x;
  const int bx = blockIdx.x;

  if (bx < 512) {
    const int m = bx & 15;
    const int b0 = (bx >> 4) * 16;
    const float4* S4 = (const float4*)(state + (size_t)b0 * 128);
    float4* sSt4 = (float4*)sSt;
    sSt4[tid] = S4[tid];
    sSt4[tid + 256] = S4[tid + 256];
    sPhi[tid] = phi[b0 * 16 + tid];
    __syncthreads();

    const int h2 = tid & 63;    // h in {h2, h2+64}
    const int rgrp = tid >> 6;  // wave id == row group (rows rgrp*4..+3)
    const float* Ap = A + (size_t)m * 16384 + h2;
    const float* Bp = Bin + (size_t)m * 2048 + h2;

    float acc[2][4];
#pragma unroll
    for (int hi = 0; hi < 2; ++hi)
#pragma unroll
      for (int j = 0; j < 4; ++j) acc[hi][j] = 0.f;

    // state @ A_m : A direct from global (L2-resident, coalesced 256B rows)
#pragma unroll 4
    for (int c = 0; c < 32; ++c) {
      float a0[4], a1[4];
#pragma unroll
      for (int u = 0; u < 4; ++u) {
        a0[u] = Ap[(size_t)(c * 4 + u) * 128];
        a1[u] = Ap[(size_t)(c * 4 + u) * 128 + 64];
      }
#pragma unroll
      for (int j = 0; j < 4; ++j) {
        const f32x4 sv = *(const f32x4*)&sSt[(rgrp * 4 + j) * 128 + c * 4];
#pragma unroll
        for (int u = 0; u < 4; ++u) {
          acc[0][j] = fmaf(sv[u], a0[u], acc[0][j]);
          acc[1][j] = fmaf(sv[u], a1[u], acc[1][j]);
        }
      }
    }
    // phi @ B_m
#pragma unroll
    for (int pc = 0; pc < 4; ++pc) {
      float b0v[4], b1v[4];
#pragma unroll
      for (int u = 0; u < 4; ++u) {
        b0v[u] = Bp[(size_t)(pc * 4 + u) * 128];
        b1v[u] = Bp[(size_t)(pc * 4 + u) * 128 + 64];
      }
#pragma unroll
      for (int j = 0; j < 4; ++j) {
        const f32x4 pv = *(const f32x4*)&sPhi[(rgrp * 4 + j) * 16 + pc * 4];
#pragma unroll
        for (int u = 0; u < 4; ++u) {
          acc[0][j] = fmaf(pv[u], b0v[u], acc[0][j]);
          acc[1][j] = fmaf(pv[u], b1v[u], acc[1][j]);
        }
      }
    }

    // tanh, outputs, per-row squared-norm (whole row lives in one wave)
#pragma unroll
    for (int j = 0; j < 4; ++j) {
      const int row = rgrp * 4 + j;
      const int R = (b0 + row) * 16 + m;
      const float v0 = tanhf(acc[0][j]);
      const float v1 = tanhf(acc[1][j]);
      __builtin_nontemporal_store(v0, &ns_out[(size_t)R * 128 + h2]);
      __builtin_nontemporal_store(v1, &ns_out[(size_t)R * 128 + h2 + 64]);
      sRes[row * 128 + h2] = v0;
      sRes[row * 128 + h2 + 64] = v1;
      float s = v0 * v0 + v1 * v1;
#pragma unroll
      for (int o = 32; o > 0; o >>= 1) s += __shfl_xor(s, o);
      if (h2 == 0) s_sq[R] = s;
    }
    __syncthreads();

    // repack to swizzled bf16: one 16B chunk per thread
    {
      const int row = tid >> 4;  // 0..15
      const int kb = tid & 15;   // chunk index
      const f32x4 r0 = *(const f32x4*)&sRes[row * 128 + kb * 8];
      const f32x4 r1 = *(const f32x4*)&sRes[row * 128 + kb * 8 + 4];
      bf16x8 o;
#pragma unroll
      for (int i = 0; i < 4; ++i) {
        o[i] = (__bf16)r0[i];
        o[i + 4] = (__bf16)r1[i];
      }
      const int R = (b0 + row) * 16 + m;  // R & 15 == m
      *(bf16x8*)(ns_bf + (size_t)R * 128 + ((kb ^ m) * 8)) = o;
    }
  } else {
    // trajectory prep: 128 rows per block, 2 threads per row
    const int t0 = (bx - 512) * 128;
    const int t = t0 + (tid >> 1);
    const int half = tid & 1;
    float s = 0.f;
#pragma unroll
    for (int q = 0; q < 8; ++q) {
      const int kb = half * 8 + q;
      const f32x4 v0 = *(const f32x4*)&traj[(size_t)t * 128 + kb * 8];
      const f32x4 v1 = *(const f32x4*)&traj[(size_t)t * 128 + kb * 8 + 4];
      s += v0[0] * v0[0] + v0[1] * v0[1] + v0[2] * v0[2] + v0[3] * v0[3];
      s += v1[0] * v1[0] + v1[1] * v1[1] + v1[2] * v1[2] + v1[3] * v1[3];
      bf16x8 o;
#pragma unroll
      for (int i = 0; i < 4; ++i) {
        o[i] = (__bf16)v0[i];
        o[i + 4] = (__bf16)v1[i];
      }
      *(bf16x8*)(tj_bf + (size_t)t * 128 + ((kb ^ (t & 15)) * 8)) = o;
    }
    s += __shfl_xor(s, 1);  // combine the row's two halves (adjacent lanes)
    if (half == 0) t_sq[t] = s;
  }
}

// ---------------------------------------------------------------------------
// Kernel 2: sim[R, t] = exp(-max(s_sq[R] + t_sq[t] - 2 * <ns[R,:], traj[t,:]>, 0))
// 128x128 tile; traj tile (32 KB) + ns tile in TWO 64-row halves (16 KB) so
// LDS = ~49 KB -> 3 blocks/CU. Half-1 restage DMA overlaps half-0 epilogue.
// MFMA with traj as A operand -> lane's 4 acc regs = 4 consecutive t ->
// float4 nontemporal stores.
// ---------------------------------------------------------------------------
__global__ __launch_bounds__(256) void sim_kernel(
    const __bf16* __restrict__ ns_bf, const __bf16* __restrict__ tj_bf,
    const float* __restrict__ s_sq, const float* __restrict__ t_sq,
    float* __restrict__ out) {
  __shared__ alignas(16) __bf16 sB[128 * 128];  // 32 KB traj (swizzled)
  __shared__ alignas(16) __bf16 sA[64 * 128];   // 16 KB ns half (swizzled)
  __shared__ float sSq[128];
  __shared__ float sTq[128];
  const int tid = threadIdx.x;
  const int lane = tid & 63;
  const int w = tid >> 6;
  const int R0 = blockIdx.x * 128;
  const int C0 = blockIdx.y * 128;

  const char* gB = (const char*)(tj_bf + (size_t)C0 * 128);
  const char* gA = (const char*)(ns_bf + (size_t)R0 * 128);
#pragma unroll
  for (int it = 0; it < 8; ++it) {
    const int off = w * 8192 + it * 1024;  // wave-uniform base; HW adds lane*16
    gload_lds16(gB + off + lane * 16, (char*)sB + off);
  }
#pragma unroll
  for (int it = 0; it < 4; ++it) {
    const int off = w * 4096 + it * 1024;
    gload_lds16(gA + off + lane * 16, (char*)sA + off);
  }
  if (tid < 128)
    sSq[tid] = s_sq[R0 + tid];
  else
    sTq[tid - 128] = t_sq[C0 + tid - 128];
  __syncthreads();

  const int abase = (w >> 1) * 32;  // wave's 32 ns-rows within the 64-row half
  const int cbase = (w & 1) * 64;   // wave's 64 traj-rows
  const int l15 = lane & 15;
  const int quad = lane >> 4;

  f32x4 acc[2][4];

#pragma unroll
  for (int half = 0; half < 2; ++half) {
#pragma unroll
    for (int i = 0; i < 2; ++i)
#pragma unroll
      for (int j = 0; j < 4; ++j) acc[i][j] = (f32x4){0.f, 0.f, 0.f, 0.f};

#pragma unroll
    for (int ks = 0; ks < 4; ++ks) {
      const int kb = quad + ks * 4;     // unswizzled chunk index
      const int koff = (kb ^ l15) * 8;  // swizzled element offset
      bf16x8 af[2], bfr[4];
#pragma unroll
      for (int i = 0; i < 2; ++i)
        af[i] = *(const bf16x8*)&sA[(abase + i * 16 + l15) * 128 + koff];
#pragma unroll
      for (int i = 0; i < 4; ++i)
        bfr[i] = *(const bf16x8*)&sB[(cbase + i * 16 + l15) * 128 + koff];
#pragma unroll
      for (int ri = 0; ri < 2; ++ri)
#pragma unroll
        for (int ci = 0; ci < 4; ++ci)
          acc[ri][ci] = __builtin_amdgcn_mfma_f32_16x16x32_bf16(
              bfr[ci], af[ri], acc[ri][ci], 0, 0, 0);  // A=traj, B=ns
    }

    if (half == 0) {
      // all waves done reading sA half 0; restage half 1 behind the epilogue
      __syncthreads();
#pragma unroll
      for (int it = 0; it < 4; ++it) {
        const int off = w * 4096 + it * 1024;
        gload_lds16(gA + 16384 + off + lane * 16, (char*)sA + off);
      }
    }

    // epilogue: D row(quad*4+reg) = t, col(lane&15) = ns row
#pragma unroll
    for (int ri = 0; ri < 2; ++ri) {
      const int lrow = half * 64 + abase + ri * 16 + l15;  // local ns row
      const float sq = sSq[lrow];
      float* orow = out + (size_t)(R0 + lrow) * NT + C0;
#pragma unroll
      for (int ci = 0; ci < 4; ++ci) {
        const int t4 = cbase + ci * 16 + quad * 4;
        const f32x4 tq = *(const f32x4*)&sTq[t4];
        f32x4 r;
#pragma unroll
        for (int k = 0; k < 4; ++k) {
          const float d = fmaxf(sq + tq[k] - 2.f * acc[ri][ci][k], 0.f);
          r[k] = __expf(-d);
        }
        __builtin_nontemporal_store(r, (f32x4*)&orow[t4]);
      }
    }

    if (half == 0) __syncthreads();  // drain half-1 restage
  }
}

// ---------------------------------------------------------------------------
extern "C" void kernel_launch(void* const* d_in, const int* in_sizes, int n_in,
                              void* d_out, int out_size, void* d_ws,
                              size_t ws_size, hipStream_t stream) {
  (void)in_sizes; (void)n_in; (void)out_size; (void)ws_size;
  const float* phi   = (const float*)d_in[0];
  const float* state = (const float*)d_in[1];
  const float* traj  = (const float*)d_in[2];
  const float* A     = (const float*)d_in[3];
  const float* Bin   = (const float*)d_in[4];

  float* out = (float*)d_out;
  float* out_ns = out + (size_t)NB * NM * NT;  // second output: new_state fp32

  char* ws = (char*)d_ws;
  __bf16* ns_bf = (__bf16*)ws;                              // 2 MB
  __bf16* tj_bf = (__bf16*)(ws + (2u << 20));               // 1 MB
  float* s_sq   = (float*)(ws + (3u << 20));                // 32 KB
  float* t_sq   = (float*)(ws + (3u << 20) + (32u << 10));  // 16 KB

  prep_kernel<<<544, 256, 0, stream>>>(phi, state, traj, A, Bin, out_ns, ns_bf,
                                       tj_bf, s_sq, t_sq);
  dim3 g2(NB * NM / 128, NT / 128);  // 64 x 32
  sim_kernel<<<g2, 256, 0, stream>>>(ns_bf, tj_bf, s_sq, t_sq, out);
}

// Round 4
// 173.568 us; speedup vs baseline: 1.2373x; 1.2373x over previous
//
#include <hip/hip_runtime.h>
#include <hip/hip_bf16.h>
#include <cstdint>
#include <cstddef>

// Problem constants
#define NB 512
#define NM 16
#define ND 128
#define NP 16
#define NT 4096

typedef __bf16 bf16x8 __attribute__((ext_vector_type(8)));
typedef float f32x4 __attribute__((ext_vector_type(4)));

static_assert(sizeof(bf16x8) == 16, "bf16x8 must be 16B");

__device__ __forceinline__ void gload_lds16(const void* g, void* l) {
  __builtin_amdgcn_global_load_lds(
      (const __attribute__((address_space(1))) unsigned int*)g,
      (__attribute__((address_space(3))) unsigned int*)l, 16, 0, 0);
}

// ---------------------------------------------------------------------------
// Kernel 1 (identical to R2 known-good):
//  blocks [0,512): new_state[b,m,:] = tanh(state@A_m + phi@B_m)
//    -> fp32 to d_out tail, swizzled bf16 to ws, s_sq[b*16+m] to ws
//  blocks [512,544): t_sq[t] + swizzled bf16 trajectories
//  Swizzle: 16B chunk kb of row R stored at chunk (kb ^ (R&15)) -> conflict-
//  free ds_read_b128 fragment reads in kernel 2.
// ---------------------------------------------------------------------------
__global__ __launch_bounds__(256) void prep_kernel(
    const float* __restrict__ phi, const float* __restrict__ state,
    const float* __restrict__ traj, const float* __restrict__ A,
    const float* __restrict__ Bin, float* __restrict__ ns_out,
    __bf16* __restrict__ ns_bf, __bf16* __restrict__ tj_bf,
    float* __restrict__ s_sq, float* __restrict__ t_sq) {
  __shared__ alignas(16) float sSt[16 * 128];   // state rows (8 KB)
  __shared__ alignas(16) float sPhi[16 * 16];   // phi rows (1 KB)
  __shared__ alignas(16) float sRes[16 * 128];  // result tile for repack (8 KB)
  const int tid = threadIdx.x;
  const int bx = blockIdx.x;

  if (bx < 512) {
    const int m = bx & 15;
    const int b0 = (bx >> 4) * 16;
    const float4* S4 = (const float4*)(state + (size_t)b0 * 128);
    float4* sSt4 = (float4*)sSt;
    sSt4[tid] = S4[tid];
    sSt4[tid + 256] = S4[tid + 256];
    sPhi[tid] = phi[b0 * 16 + tid];
    __syncthreads();

    const int h2 = tid & 63;    // h in {h2, h2+64}
    const int rgrp = tid >> 6;  // wave id == row group (rows rgrp*4..+3)
    const float* Ap = A + (size_t)m * 16384 + h2;
    const float* Bp = Bin + (size_t)m * 2048 + h2;

    float acc[2][4];
#pragma unroll
    for (int hi = 0; hi < 2; ++hi)
#pragma unroll
      for (int j = 0; j < 4; ++j) acc[hi][j] = 0.f;

    // state @ A_m : A direct from global (L2-resident, coalesced 256B rows)
#pragma unroll 4
    for (int c = 0; c < 32; ++c) {
      float a0[4], a1[4];
#pragma unroll
      for (int u = 0; u < 4; ++u) {
        a0[u] = Ap[(size_t)(c * 4 + u) * 128];
        a1[u] = Ap[(size_t)(c * 4 + u) * 128 + 64];
      }
#pragma unroll
      for (int j = 0; j < 4; ++j) {
        const f32x4 sv = *(const f32x4*)&sSt[(rgrp * 4 + j) * 128 + c * 4];
#pragma unroll
        for (int u = 0; u < 4; ++u) {
          acc[0][j] = fmaf(sv[u], a0[u], acc[0][j]);
          acc[1][j] = fmaf(sv[u], a1[u], acc[1][j]);
        }
      }
    }
    // phi @ B_m
#pragma unroll
    for (int pc = 0; pc < 4; ++pc) {
      float b0v[4], b1v[4];
#pragma unroll
      for (int u = 0; u < 4; ++u) {
        b0v[u] = Bp[(size_t)(pc * 4 + u) * 128];
        b1v[u] = Bp[(size_t)(pc * 4 + u) * 128 + 64];
      }
#pragma unroll
      for (int j = 0; j < 4; ++j) {
        const f32x4 pv = *(const f32x4*)&sPhi[(rgrp * 4 + j) * 16 + pc * 4];
#pragma unroll
        for (int u = 0; u < 4; ++u) {
          acc[0][j] = fmaf(pv[u], b0v[u], acc[0][j]);
          acc[1][j] = fmaf(pv[u], b1v[u], acc[1][j]);
        }
      }
    }

    // tanh, outputs, per-row squared-norm (whole row lives in one wave)
#pragma unroll
    for (int j = 0; j < 4; ++j) {
      const int row = rgrp * 4 + j;
      const int R = (b0 + row) * 16 + m;
      const float v0 = tanhf(acc[0][j]);
      const float v1 = tanhf(acc[1][j]);
      ns_out[(size_t)R * 128 + h2] = v0;
      ns_out[(size_t)R * 128 + h2 + 64] = v1;
      sRes[row * 128 + h2] = v0;
      sRes[row * 128 + h2 + 64] = v1;
      float s = v0 * v0 + v1 * v1;
#pragma unroll
      for (int o = 32; o > 0; o >>= 1) s += __shfl_xor(s, o);
      if (h2 == 0) s_sq[R] = s;
    }
    __syncthreads();

    // repack to swizzled bf16: one 16B chunk per thread
    {
      const int row = tid >> 4;  // 0..15
      const int kb = tid & 15;   // chunk index
      const f32x4 r0 = *(const f32x4*)&sRes[row * 128 + kb * 8];
      const f32x4 r1 = *(const f32x4*)&sRes[row * 128 + kb * 8 + 4];
      bf16x8 o;
#pragma unroll
      for (int i = 0; i < 4; ++i) {
        o[i] = (__bf16)r0[i];
        o[i + 4] = (__bf16)r1[i];
      }
      const int R = (b0 + row) * 16 + m;  // R & 15 == m
      *(bf16x8*)(ns_bf + (size_t)R * 128 + ((kb ^ m) * 8)) = o;
    }
  } else {
    // trajectory prep: 128 rows per block, 2 threads per row
    const int t0 = (bx - 512) * 128;
    const int t = t0 + (tid >> 1);
    const int half = tid & 1;
    float s = 0.f;
#pragma unroll
    for (int q = 0; q < 8; ++q) {
      const int kb = half * 8 + q;
      const f32x4 v0 = *(const f32x4*)&traj[(size_t)t * 128 + kb * 8];
      const f32x4 v1 = *(const f32x4*)&traj[(size_t)t * 128 + kb * 8 + 4];
      s += v0[0] * v0[0] + v0[1] * v0[1] + v0[2] * v0[2] + v0[3] * v0[3];
      s += v1[0] * v1[0] + v1[1] * v1[1] + v1[2] * v1[2] + v1[3] * v1[3];
      bf16x8 o;
#pragma unroll
      for (int i = 0; i < 4; ++i) {
        o[i] = (__bf16)v0[i];
        o[i + 4] = (__bf16)v1[i];
      }
      *(bf16x8*)(tj_bf + (size_t)t * 128 + ((kb ^ (t & 15)) * 8)) = o;
    }
    s += __shfl_xor(s, 1);  // combine the row's two halves (adjacent lanes)
    if (half == 0) t_sq[t] = s;
  }
}

// ---------------------------------------------------------------------------
// Kernel 2: sim[R, t] = exp(-max(s_sq[R] + t_sq[t] - 2 * <ns[R,:], traj[t,:]>, 0))
// 64(ns rows) x 128(traj) tile -> LDS 48.8 KB -> 3 blocks/CU (was 2 at 64.5).
// Single-stage, no mid-kernel barriers (R3's restage regressed). MFMA with
// traj as A operand -> lane's 4 acc regs = 4 consecutive t -> float4 stores.
// ---------------------------------------------------------------------------
__global__ __launch_bounds__(256) void sim_kernel(
    const __bf16* __restrict__ ns_bf, const __bf16* __restrict__ tj_bf,
    const float* __restrict__ s_sq, const float* __restrict__ t_sq,
    float* __restrict__ out) {
  __shared__ alignas(16) __bf16 sA[64 * 128];   // 16 KB ns rows (swizzled)
  __shared__ alignas(16) __bf16 sB[128 * 128];  // 32 KB traj rows (swizzled)
  __shared__ float sSq[64];
  __shared__ float sTq[128];
  const int tid = threadIdx.x;
  const int lane = tid & 63;
  const int w = tid >> 6;
  const int R0 = blockIdx.x * 64;
  const int C0 = blockIdx.y * 128;

  // async stage: contiguous images (swizzle is inside rows, preserved)
  const char* gA = (const char*)(ns_bf + (size_t)R0 * 128);
  const char* gB = (const char*)(tj_bf + (size_t)C0 * 128);
#pragma unroll
  for (int it = 0; it < 4; ++it) {
    const int off = w * 4096 + it * 1024;  // wave-uniform base; HW adds lane*16
    gload_lds16(gA + off + lane * 16, (char*)sA + off);
  }
#pragma unroll
  for (int it = 0; it < 8; ++it) {
    const int off = w * 8192 + it * 1024;
    gload_lds16(gB + off + lane * 16, (char*)sB + off);
  }
  if (tid < 64)
    sSq[tid] = s_sq[R0 + tid];
  else if (tid < 192)
    sTq[tid - 64] = t_sq[C0 + tid - 64];
  __syncthreads();

  const int abase = (w >> 1) * 32;  // wave's 32 ns rows
  const int cbase = (w & 1) * 64;   // wave's 64 traj rows
  const int l15 = lane & 15;
  const int quad = lane >> 4;

  f32x4 acc[2][4];  // [ri = ns subtile][ci = traj subtile]
#pragma unroll
  for (int i = 0; i < 2; ++i)
#pragma unroll
    for (int j = 0; j < 4; ++j) acc[i][j] = (f32x4){0.f, 0.f, 0.f, 0.f};

#pragma unroll
  for (int ks = 0; ks < 4; ++ks) {
    const int kb = quad + ks * 4;     // unswizzled chunk index
    const int koff = (kb ^ l15) * 8;  // swizzled element offset
    bf16x8 af[2], bfr[4];
#pragma unroll
    for (int i = 0; i < 2; ++i)
      af[i] = *(const bf16x8*)&sA[(abase + i * 16 + l15) * 128 + koff];
#pragma unroll
    for (int i = 0; i < 4; ++i)
      bfr[i] = *(const bf16x8*)&sB[(cbase + i * 16 + l15) * 128 + koff];
#pragma unroll
    for (int ri = 0; ri < 2; ++ri)
#pragma unroll
      for (int ci = 0; ci < 4; ++ci)
        acc[ri][ci] = __builtin_amdgcn_mfma_f32_16x16x32_bf16(
            bfr[ci], af[ri], acc[ri][ci], 0, 0, 0);  // A=traj, B=ns
  }

  // D layout: col(lane&15) = ns row, row(quad*4+reg) = t -> float4 along t
#pragma unroll
  for (int ri = 0; ri < 2; ++ri) {
    const int nsrow = abase + ri * 16 + l15;
    const float sq = sSq[nsrow];
    float* orow = out + (size_t)(R0 + nsrow) * NT + C0;
#pragma unroll
    for (int ci = 0; ci < 4; ++ci) {
      const int t4 = cbase + ci * 16 + quad * 4;
      const f32x4 tq = *(const f32x4*)&sTq[t4];
      f32x4 r;
#pragma unroll
      for (int k = 0; k < 4; ++k) {
        const float d = fmaxf(sq + tq[k] - 2.f * acc[ri][ci][k], 0.f);
        r[k] = __expf(-d);
      }
      *(f32x4*)&orow[t4] = r;
    }
  }
}

// ---------------------------------------------------------------------------
extern "C" void kernel_launch(void* const* d_in, const int* in_sizes, int n_in,
                              void* d_out, int out_size, void* d_ws,
                              size_t ws_size, hipStream_t stream) {
  (void)in_sizes; (void)n_in; (void)out_size; (void)ws_size;
  const float* phi   = (const float*)d_in[0];
  const float* state = (const float*)d_in[1];
  const float* traj  = (const float*)d_in[2];
  const float* A     = (const float*)d_in[3];
  const float* Bin   = (const float*)d_in[4];

  float* out = (float*)d_out;
  float* out_ns = out + (size_t)NB * NM * NT;  // second output: new_state fp32

  char* ws = (char*)d_ws;
  __bf16* ns_bf = (__bf16*)ws;                              // 2 MB
  __bf16* tj_bf = (__bf16*)(ws + (2u << 20));               // 1 MB
  float* s_sq   = (float*)(ws + (3u << 20));                // 32 KB
  float* t_sq   = (float*)(ws + (3u << 20) + (32u << 10));  // 16 KB

  prep_kernel<<<544, 256, 0, stream>>>(phi, state, traj, A, Bin, out_ns, ns_bf,
                                       tj_bf, s_sq, t_sq);
  dim3 g2(NB * NM / 64, NT / 128);  // 128 x 32
  sim_kernel<<<g2, 256, 0, stream>>>(ns_bf, tj_bf, s_sq, t_sq, out);
}

// Round 5
// 169.978 us; speedup vs baseline: 1.2635x; 1.0211x over previous
//
#include <hip/hip_runtime.h>
#include <hip/hip_bf16.h>
#include <cstdint>
#include <cstddef>

// Problem constants
#define NB 512
#define NM 16
#define ND 128
#define NP 16
#define NT 4096

typedef __bf16 bf16x8 __attribute__((ext_vector_type(8)));
typedef float f32x4 __attribute__((ext_vector_type(4)));

static_assert(sizeof(bf16x8) == 16, "bf16x8 must be 16B");

__device__ __forceinline__ void gload_lds16(const void* g, void* l) {
  __builtin_amdgcn_global_load_lds(
      (const __attribute__((address_space(1))) unsigned int*)g,
      (__attribute__((address_space(3))) unsigned int*)l, 16, 0, 0);
}

// ---------------------------------------------------------------------------
// Kernel 1 (identical to R2 known-good):
//  blocks [0,512): new_state[b,m,:] = tanh(state@A_m + phi@B_m)
//    -> fp32 to d_out tail, swizzled bf16 to ws, s_sq[b*16+m] to ws
//  blocks [512,544): t_sq[t] + swizzled bf16 trajectories
//  Swizzle: 16B chunk kb of row R stored at chunk (kb ^ (R&15)) -> conflict-
//  free ds_read_b128 fragment reads in kernel 2.
// ---------------------------------------------------------------------------
__global__ __launch_bounds__(256) void prep_kernel(
    const float* __restrict__ phi, const float* __restrict__ state,
    const float* __restrict__ traj, const float* __restrict__ A,
    const float* __restrict__ Bin, float* __restrict__ ns_out,
    __bf16* __restrict__ ns_bf, __bf16* __restrict__ tj_bf,
    float* __restrict__ s_sq, float* __restrict__ t_sq) {
  __shared__ alignas(16) float sSt[16 * 128];   // state rows (8 KB)
  __shared__ alignas(16) float sPhi[16 * 16];   // phi rows (1 KB)
  __shared__ alignas(16) float sRes[16 * 128];  // result tile for repack (8 KB)
  const int tid = threadIdx.x;
  const int bx = blockIdx.x;

  if (bx < 512) {
    const int m = bx & 15;
    const int b0 = (bx >> 4) * 16;
    const float4* S4 = (const float4*)(state + (size_t)b0 * 128);
    float4* sSt4 = (float4*)sSt;
    sSt4[tid] = S4[tid];
    sSt4[tid + 256] = S4[tid + 256];
    sPhi[tid] = phi[b0 * 16 + tid];
    __syncthreads();

    const int h2 = tid & 63;    // h in {h2, h2+64}
    const int rgrp = tid >> 6;  // wave id == row group (rows rgrp*4..+3)
    const float* Ap = A + (size_t)m * 16384 + h2;
    const float* Bp = Bin + (size_t)m * 2048 + h2;

    float acc[2][4];
#pragma unroll
    for (int hi = 0; hi < 2; ++hi)
#pragma unroll
      for (int j = 0; j < 4; ++j) acc[hi][j] = 0.f;

    // state @ A_m : A direct from global (L2-resident, coalesced 256B rows)
#pragma unroll 4
    for (int c = 0; c < 32; ++c) {
      float a0[4], a1[4];
#pragma unroll
      for (int u = 0; u < 4; ++u) {
        a0[u] = Ap[(size_t)(c * 4 + u) * 128];
        a1[u] = Ap[(size_t)(c * 4 + u) * 128 + 64];
      }
#pragma unroll
      for (int j = 0; j < 4; ++j) {
        const f32x4 sv = *(const f32x4*)&sSt[(rgrp * 4 + j) * 128 + c * 4];
#pragma unroll
        for (int u = 0; u < 4; ++u) {
          acc[0][j] = fmaf(sv[u], a0[u], acc[0][j]);
          acc[1][j] = fmaf(sv[u], a1[u], acc[1][j]);
        }
      }
    }
    // phi @ B_m
#pragma unroll
    for (int pc = 0; pc < 4; ++pc) {
      float b0v[4], b1v[4];
#pragma unroll
      for (int u = 0; u < 4; ++u) {
        b0v[u] = Bp[(size_t)(pc * 4 + u) * 128];
        b1v[u] = Bp[(size_t)(pc * 4 + u) * 128 + 64];
      }
#pragma unroll
      for (int j = 0; j < 4; ++j) {
        const f32x4 pv = *(const f32x4*)&sPhi[(rgrp * 4 + j) * 16 + pc * 4];
#pragma unroll
        for (int u = 0; u < 4; ++u) {
          acc[0][j] = fmaf(pv[u], b0v[u], acc[0][j]);
          acc[1][j] = fmaf(pv[u], b1v[u], acc[1][j]);
        }
      }
    }

    // tanh, outputs, per-row squared-norm (whole row lives in one wave)
#pragma unroll
    for (int j = 0; j < 4; ++j) {
      const int row = rgrp * 4 + j;
      const int R = (b0 + row) * 16 + m;
      const float v0 = tanhf(acc[0][j]);
      const float v1 = tanhf(acc[1][j]);
      ns_out[(size_t)R * 128 + h2] = v0;
      ns_out[(size_t)R * 128 + h2 + 64] = v1;
      sRes[row * 128 + h2] = v0;
      sRes[row * 128 + h2 + 64] = v1;
      float s = v0 * v0 + v1 * v1;
#pragma unroll
      for (int o = 32; o > 0; o >>= 1) s += __shfl_xor(s, o);
      if (h2 == 0) s_sq[R] = s;
    }
    __syncthreads();

    // repack to swizzled bf16: one 16B chunk per thread
    {
      const int row = tid >> 4;  // 0..15
      const int kb = tid & 15;   // chunk index
      const f32x4 r0 = *(const f32x4*)&sRes[row * 128 + kb * 8];
      const f32x4 r1 = *(const f32x4*)&sRes[row * 128 + kb * 8 + 4];
      bf16x8 o;
#pragma unroll
      for (int i = 0; i < 4; ++i) {
        o[i] = (__bf16)r0[i];
        o[i + 4] = (__bf16)r1[i];
      }
      const int R = (b0 + row) * 16 + m;  // R & 15 == m
      *(bf16x8*)(ns_bf + (size_t)R * 128 + ((kb ^ m) * 8)) = o;
    }
  } else {
    // trajectory prep: 128 rows per block, 2 threads per row
    const int t0 = (bx - 512) * 128;
    const int t = t0 + (tid >> 1);
    const int half = tid & 1;
    float s = 0.f;
#pragma unroll
    for (int q = 0; q < 8; ++q) {
      const int kb = half * 8 + q;
      const f32x4 v0 = *(const f32x4*)&traj[(size_t)t * 128 + kb * 8];
      const f32x4 v1 = *(const f32x4*)&traj[(size_t)t * 128 + kb * 8 + 4];
      s += v0[0] * v0[0] + v0[1] * v0[1] + v0[2] * v0[2] + v0[3] * v0[3];
      s += v1[0] * v1[0] + v1[1] * v1[1] + v1[2] * v1[2] + v1[3] * v1[3];
      bf16x8 o;
#pragma unroll
      for (int i = 0; i < 4; ++i) {
        o[i] = (__bf16)v0[i];
        o[i + 4] = (__bf16)v1[i];
      }
      *(bf16x8*)(tj_bf + (size_t)t * 128 + ((kb ^ (t & 15)) * 8)) = o;
    }
    s += __shfl_xor(s, 1);  // combine the row's two halves (adjacent lanes)
    if (half == 0) t_sq[t] = s;
  }
}

// ---------------------------------------------------------------------------
// Kernel 2: sim[R, t] = exp(-max(s_sq[R] + t_sq[t] - 2 * <ns[R,:], traj[t,:]>, 0))
// Persistent block: 128 ns-rows x (4 C-tiles of 64 traj cols). sA staged ONCE
// (32 KB); sB double-buffered 2x16 KB with the j+1 prefetch issued right
// after the barrier that opens tile j (drain happens a full compute phase
// later). One barrier per tile. LDS ~65.8 KB -> 2 blocks/CU.
// MFMA A=traj, B=ns -> lane's 4 acc regs = 4 consecutive t -> float4 stores.
// ---------------------------------------------------------------------------
__global__ __launch_bounds__(256) void sim_kernel(
    const __bf16* __restrict__ ns_bf, const __bf16* __restrict__ tj_bf,
    const float* __restrict__ s_sq, const float* __restrict__ t_sq,
    float* __restrict__ out) {
  __shared__ alignas(16) __bf16 sA[128 * 128];     // 32 KB ns rows (swizzled)
  __shared__ alignas(16) __bf16 sB[2][64 * 128];   // 2x16 KB traj (swizzled)
  __shared__ float sSq[128];
  __shared__ float sTq[256];
  const int tid = threadIdx.x;
  const int lane = tid & 63;
  const int w = tid >> 6;
  const int R0 = blockIdx.x * 128;   // 64 R-tiles
  const int Cg = blockIdx.y * 256;   // 16 C-groups of 4x64 cols

  const char* gA = (const char*)(ns_bf + (size_t)R0 * 128);
  const char* gB = (const char*)(tj_bf + (size_t)Cg * 128);

  // stage sA (once) + sB[0]
#pragma unroll
  for (int it = 0; it < 8; ++it) {
    const int off = w * 8192 + it * 1024;  // wave-uniform base; HW adds lane*16
    gload_lds16(gA + off + lane * 16, (char*)sA + off);
  }
#pragma unroll
  for (int it = 0; it < 4; ++it) {
    const int off = w * 4096 + it * 1024;
    gload_lds16(gB + off + lane * 16, (char*)sB[0] + off);
  }
  if (tid < 128)
    sSq[tid] = s_sq[R0 + tid];
  sTq[tid] = t_sq[Cg + tid];

  const int abase = w * 32;        // wave's 32 ns rows (of 128)
  const int l15 = lane & 15;
  const int quad = lane >> 4;

  __syncthreads();  // drains sA + sB[0] DMA

#pragma unroll
  for (int j = 0; j < 4; ++j) {
    const int cur = j & 1;
    // prefetch next C-tile into the other buffer; its drain happens at the
    // NEXT barrier, a full compute+epilogue later.
    if (j < 3) {
#pragma unroll
      for (int it = 0; it < 4; ++it) {
        const int off = w * 4096 + it * 1024;
        gload_lds16(gB + (size_t)(j + 1) * 16384 + off + lane * 16,
                    (char*)sB[1 - cur] + off);
      }
    }

    f32x4 acc[2][4];
#pragma unroll
    for (int i = 0; i < 2; ++i)
#pragma unroll
      for (int c = 0; c < 4; ++c) acc[i][c] = (f32x4){0.f, 0.f, 0.f, 0.f};

#pragma unroll
    for (int ks = 0; ks < 4; ++ks) {
      const int kb = quad + ks * 4;     // unswizzled chunk index
      const int koff = (kb ^ l15) * 8;  // swizzled element offset
      bf16x8 af[2], bfr[4];
#pragma unroll
      for (int i = 0; i < 2; ++i)
        af[i] = *(const bf16x8*)&sA[(abase + i * 16 + l15) * 128 + koff];
#pragma unroll
      for (int c = 0; c < 4; ++c)
        bfr[c] = *(const bf16x8*)&sB[cur][(c * 16 + l15) * 128 + koff];
#pragma unroll
      for (int ri = 0; ri < 2; ++ri)
#pragma unroll
        for (int ci = 0; ci < 4; ++ci)
          acc[ri][ci] = __builtin_amdgcn_mfma_f32_16x16x32_bf16(
              bfr[ci], af[ri], acc[ri][ci], 0, 0, 0);  // A=traj, B=ns
    }

    // epilogue: D row(quad*4+reg) = t, col(lane&15) = ns row
#pragma unroll
    for (int ri = 0; ri < 2; ++ri) {
      const int nsrow = abase + ri * 16 + l15;
      const float sq = sSq[nsrow];
      float* orow = out + (size_t)(R0 + nsrow) * NT + Cg + j * 64;
#pragma unroll
      for (int ci = 0; ci < 4; ++ci) {
        const int t4 = ci * 16 + quad * 4;
        const f32x4 tq = *(const f32x4*)&sTq[j * 64 + t4];
        f32x4 r;
#pragma unroll
        for (int k = 0; k < 4; ++k) {
          const float d = fmaxf(sq + tq[k] - 2.f * acc[ri][ci][k], 0.f);
          r[k] = __expf(-d);
        }
        *(f32x4*)&orow[t4] = r;
      }
    }

    if (j < 3) __syncthreads();  // everyone done with sB[cur]; next prefetch landed
  }
}

// ---------------------------------------------------------------------------
extern "C" void kernel_launch(void* const* d_in, const int* in_sizes, int n_in,
                              void* d_out, int out_size, void* d_ws,
                              size_t ws_size, hipStream_t stream) {
  (void)in_sizes; (void)n_in; (void)out_size; (void)ws_size;
  const float* phi   = (const float*)d_in[0];
  const float* state = (const float*)d_in[1];
  const float* traj  = (const float*)d_in[2];
  const float* A     = (const float*)d_in[3];
  const float* Bin   = (const float*)d_in[4];

  float* out = (float*)d_out;
  float* out_ns = out + (size_t)NB * NM * NT;  // second output: new_state fp32

  char* ws = (char*)d_ws;
  __bf16* ns_bf = (__bf16*)ws;                              // 2 MB
  __bf16* tj_bf = (__bf16*)(ws + (2u << 20));               // 1 MB
  float* s_sq   = (float*)(ws + (3u << 20));                // 32 KB
  float* t_sq   = (float*)(ws + (3u << 20) + (32u << 10));  // 16 KB

  prep_kernel<<<544, 256, 0, stream>>>(phi, state, traj, A, Bin, out_ns, ns_bf,
                                       tj_bf, s_sq, t_sq);
  dim3 g2(NB * NM / 128, NT / 256);  // 64 x 16, each block does 4 C-tiles
  sim_kernel<<<g2, 256, 0, stream>>>(ns_bf, tj_bf, s_sq, t_sq, out);
}